// Round 5
// baseline (1464.091 us; speedup 1.0000x reference)
//
#include <hip/hip_runtime.h>

namespace {

constexpr int kB = 64;
constexpr int kL = 4096;
constexpr float kLrW = 1.0f / 64.0f;
constexpr float kLrF = 1.0f / 128.0f;
constexpr float kGradMax = 30.0f;
constexpr float kEps = 1e-9f;
constexpr int kPF = 8;                 // steps per chunk
constexpr int kNC = kL / kPF;          // 512 chunks

#define DPP_ADD_F32(v, ctrl)                                                   \
    v += __int_as_float(__builtin_amdgcn_update_dpp(                           \
        0, __float_as_int(v), (ctrl), 0xF, 0xF, true))

// 32-lane-group sum: lane31 = sum(lanes 0..31), lane63 = sum(lanes 32..63)
__device__ __forceinline__ float red5(float v) {
    DPP_ADD_F32(v, 0x111);  // row_shr:1
    DPP_ADD_F32(v, 0x112);  // row_shr:2
    DPP_ADD_F32(v, 0x114);  // row_shr:4
    DPP_ADD_F32(v, 0x118);  // row_shr:8
    DPP_ADD_F32(v, 0x142);  // row_bcast:15
    return v;
}

__device__ __forceinline__ float rl(float v, int l) {
    return __int_as_float(__builtin_amdgcn_readlane(__float_as_int(v), l));
}

__device__ __forceinline__ float frcp(float x) { return __builtin_amdgcn_rcpf(x); }
__device__ __forceinline__ float frsq(float x) { return __builtin_amdgcn_rsqf(x); }

__global__ __launch_bounds__(64, 1) void adf_kernel(
    const float* __restrict__ u_r, const float* __restrict__ u_i,
    const float* __restrict__ x_r, const float* __restrict__ x_i,
    const float* __restrict__ w0r_g, const float* __restrict__ w0i_g,
    const float* __restrict__ f0r_g, const float* __restrict__ f0i_g,
    float* __restrict__ out)
{
    const int b = blockIdx.x;
    const int lane = threadIdx.x;     // 0..63
    const int half = lane >> 5;       // output mode this lane owns
    const int tap  = lane & 31;
    const bool lo  = (half == 0);

    // w flat: b*128 + i*64 + j*32 + tap ; lane owns w[half][0][tap], w[half][1][tap]
    const int wbase = b * 128 + half * 64 + tap;
    float wAr = w0r_g[wbase],      wAi = w0i_g[wbase];
    float wBr = w0r_g[wbase + 32], wBi = w0i_g[wbase + 32];

    float fr = f0r_g[b * 2 + half];
    float fi = f0i_g[b * 2 + half];
    float invf0 = frsq(fr * fr + fi * fi);
    float psr = fr * invf0, psm = -fi * invf0;   // psi = conj(f)/|f|

    const float2* __restrict__ ur2 = (const float2*)u_r + (size_t)b * kL * 32;
    const float2* __restrict__ ui2 = (const float2*)u_i + (size_t)b * kL * 32;
    const float2* __restrict__ xr2 = (const float2*)x_r + (size_t)b * kL;
    const float2* __restrict__ xi2 = (const float2*)x_i + (size_t)b * kL;
    float2* __restrict__ ob2 = (float2*)out + (size_t)b * kL * 2;

    float2 AuR[kPF], AuI[kPF], AdR[kPF], AdI[kPF];
    float2 BuR[kPF], BuI[kPF], BdR[kPF], BdI[kPF];
    float suA[kPF], suB[kPF];
    float GAr[kPF], GAi[kPF], GBr[kPF], GBi[kPF];   // [7] filled late (boundary)

    auto loadChunk = [&](float2 (&uR)[kPF], float2 (&uI)[kPF],
                         float2 (&dR)[kPF], float2 (&dI)[kPF], int chunk) {
#pragma unroll
        for (int s = 0; s < kPF; ++s) {
            int t = chunk * kPF + s;
            t = t < kL ? t : kL - 1;
            uR[s] = ur2[(size_t)t * 32 + tap];
            uI[s] = ui2[(size_t)t * 32 + tap];
            dR[s] = xr2[t];
            dI[s] = xi2[t];
        }
    };

    // G(a,b) = sum conj(ua)*ub over (tap,j); result broadcast via lane31
    auto gram = [&](float2 aR, float2 aI, float2 bR, float2 bI,
                    float& Gr, float& Gi) {
        float gr = aR.x * bR.x;
        gr = fmaf(aI.x, bI.x, gr); gr = fmaf(aR.y, bR.y, gr); gr = fmaf(aI.y, bI.y, gr);
        float gi = aR.x * bI.x;
        gi = fmaf(-aI.x, bR.x, gi); gi = fmaf(aR.y, bI.y, gi); gi = fmaf(-aI.y, bR.y, gi);
        gr = red5(gr); gi = red5(gi);
        Gr = rl(gr, 31);
        Gi = rl(gi, 31);
    };

    // Per-chunk state-independent precompute: su[0..7], G[0..6] (16 indep chains)
    auto calcPre = [&](float2 (&uR)[kPF], float2 (&uI)[kPF],
                       float (&su)[kPF], float (&Gr)[kPF], float (&Gi)[kPF]) {
#pragma unroll
        for (int s = 0; s < kPF; ++s) {
            float e = uR[s].x * uR[s].x;
            e = fmaf(uR[s].y, uR[s].y, e);
            e = fmaf(uI[s].x, uI[s].x, e);
            e = fmaf(uI[s].y, uI[s].y, e);
            e = red5(e);
            su[s] = kLrW * frcp(rl(e, 31) + kEps);
        }
#pragma unroll
        for (int s = 0; s < kPF - 1; ++s)
            gram(uR[s], uI[s], uR[s + 1], uI[s + 1], Gr[s], Gi[s]);
    };

    loadChunk(AuR, AuI, AdR, AdI, 0);
    loadChunk(BuR, BuI, BdR, BdI, 1);

    // ---- prologue: v(0), nv(0) by direct reduce ----
    float vr, vi, nv;
    {
        const float2 u0 = AuR[0], q0 = AuI[0];
        float pr = wAr * u0.x;
        pr = fmaf(-wAi, q0.x, pr); pr = fmaf(wBr, u0.y, pr); pr = fmaf(-wBi, q0.y, pr);
        float pi = wAr * q0.x;
        pi = fmaf(wAi, u0.x, pi); pi = fmaf(wBr, q0.y, pi); pi = fmaf(wBi, u0.y, pi);
        pr = red5(pr); pi = red5(pi);
        const float v0r = rl(pr, 31), v1r = rl(pr, 63);
        const float v0i = rl(pi, 31), v1i = rl(pi, 63);
        vr = lo ? v0r : v1r;
        vi = lo ? v0i : v1i;
        float ven = v0r * v0r;
        ven = fmaf(v0i, v0i, ven); ven = fmaf(v1r, v1r, ven); ven = fmaf(v1i, v1i, ven);
        nv = -frcp(ven + kEps);
    }

    // ---- one scan step ----
    // uc = u_t, un = u_{t+1}; G = G(t,t+1) precomputed; v/nv/f/psi/w are state.
    auto step = [&](int t, const float2 ucR, const float2 ucI,
                    const float2 unR, const float2 unI,
                    const float2 dRv, const float2 dIv,
                    const float su_cur, const float Gr, const float Gi) {
        // lookahead reduce <w(t), u(t+1)> -- has the whole step of slack
        float pr = wAr * unR.x;
        pr = fmaf(-wAi, unI.x, pr); pr = fmaf(wBr, unR.y, pr); pr = fmaf(-wBi, unI.y, pr);
        float pi = wAr * unI.x;
        pi = fmaf(wAi, unR.x, pi); pi = fmaf(wBr, unI.y, pi); pi = fmaf(wBi, unR.y, pi);
        pr = red5(pr); pi = red5(pi);

        // scalar phase for step t (per-half SIMT)
        const float dr = lo ? dRv.x : dRv.y;
        const float di = lo ? dIv.x : dIv.y;
        const float kr = vr * fr - vi * fi;
        const float ki = vr * fi + vi * fr;
        if (tap == 0) ob2[(size_t)t * 2 + half] = make_float2(kr, ki);

        const float efr = dr - kr, efi = di - ki;
        float gfr = nv * (efr * vr + efi * vi);
        float gfi = nv * (efi * vr - efr * vi);
        const float mg = gfr * gfr + gfi * gfi;
        const float sc = fminf(1.0f, kGradMax * frsq(mg));
        gfr *= sc; gfi *= sc;

        // e_w with pre-update psi; tr/ti drive both w-update and v-fixup
        const float ewr = dr * psr - di * psm - vr;
        const float ewi = dr * psm + di * psr - vi;
        const float tr = su_cur * ewr, ti = su_cur * ewi;

        // f update + psi for next step
        fr = fmaf(-kLrF, gfr, fr);
        fi = fmaf(-kLrF, gfi, fi);
        const float invf = frsq(fr * fr + fi * fi);
        psr = fr * invf; psm = -fi * invf;

        // w update (per-lane)
        wAr = fmaf(tr, ucR.x, fmaf(ti, ucI.x, wAr));
        wAi = fmaf(ti, ucR.x, fmaf(-tr, ucI.x, wAi));
        wBr = fmaf(tr, ucR.y, fmaf(ti, ucI.y, wBr));
        wBi = fmaf(ti, ucR.y, fmaf(-tr, ucI.y, wBi));

        // broadcast lookahead, own-half fixup (critical: 2 fma after selects)
        const float v0r = rl(pr, 31), v1r = rl(pr, 63);
        const float v0i = rl(pi, 31), v1i = rl(pi, 63);
        const float mor = lo ? v0r : v1r;
        const float moi = lo ? v0i : v1i;
        vr = fmaf(tr, Gr, fmaf(-ti, Gi, mor));
        vi = fmaf(tr, Gi, fmaf( ti, Gr, moi));

        // other-half fixup only feeds ven/nv (consumed mid-next-step: slack)
        const float otr = __shfl_xor(tr, 32, 64);
        const float oti = __shfl_xor(ti, 32, 64);
        const float xr_ = lo ? v1r : v0r;
        const float xi_ = lo ? v1i : v0i;
        const float oxr = fmaf(otr, Gr, fmaf(-oti, Gi, xr_));
        const float oxi = fmaf(otr, Gi, fmaf( oti, Gr, xi_));
        float ven = vr * vr;
        ven = fmaf(vi, vi, ven); ven = fmaf(oxr, oxr, ven); ven = fmaf(oxi, oxi, ven);
        nv = -frcp(ven + kEps);
    };

    // Process one chunk; boundary G (step7 -> next chunk step0) computed 2 steps
    // before use so a freshly-issued next-chunk load has time to land.
    auto processChunk = [&](int tbase,
                            float2 (&uR)[kPF], float2 (&uI)[kPF],
                            float2 (&dR)[kPF], float2 (&dI)[kPF],
                            float (&su)[kPF], float (&Gr)[kPF], float (&Gi)[kPF],
                            const float2 nR0, const float2 nI0) {
#pragma unroll
        for (int s = 0; s < kPF - 2; ++s)
            step(tbase + s, uR[s], uI[s], uR[s + 1], uI[s + 1], dR[s], dI[s],
                 su[s], Gr[s], Gi[s]);
        gram(uR[kPF - 1], uI[kPF - 1], nR0, nI0, Gr[kPF - 1], Gi[kPF - 1]);
        step(tbase + kPF - 2, uR[kPF - 2], uI[kPF - 2], uR[kPF - 1], uI[kPF - 1],
             dR[kPF - 2], dI[kPF - 2], su[kPF - 2], Gr[kPF - 2], Gi[kPF - 2]);
        step(tbase + kPF - 1, uR[kPF - 1], uI[kPF - 1], nR0, nI0,
             dR[kPF - 1], dI[kPF - 1], su[kPF - 1], Gr[kPF - 1], Gi[kPF - 1]);
    };

    for (int c = 0; c < kNC; c += 2) {
        // A holds chunk c (resident), B holds chunk c+1 (resident)
        calcPre(AuR, AuI, suA, GAr, GAi);
        processChunk(c * kPF, AuR, AuI, AdR, AdI, suA, GAr, GAi, BuR[0], BuI[0]);
        loadChunk(AuR, AuI, AdR, AdI, (c + 2 < kNC) ? c + 2 : kNC - 1);

        calcPre(BuR, BuI, suB, GBr, GBi);
        processChunk((c + 1) * kPF, BuR, BuI, BdR, BdI, suB, GBr, GBi, AuR[0], AuI[0]);
        loadChunk(BuR, BuI, BdR, BdI, (c + 3 < kNC) ? c + 3 : kNC - 1);
    }
}

} // namespace

extern "C" void kernel_launch(void* const* d_in, const int* in_sizes, int n_in,
                              void* d_out, int out_size, void* d_ws, size_t ws_size,
                              hipStream_t stream) {
    const float* u_r  = (const float*)d_in[0];
    const float* u_i  = (const float*)d_in[1];
    const float* x_r  = (const float*)d_in[2];
    const float* x_i  = (const float*)d_in[3];
    const float* w0_r = (const float*)d_in[4];
    const float* w0_i = (const float*)d_in[5];
    const float* f0_r = (const float*)d_in[6];
    const float* f0_i = (const float*)d_in[7];
    float* out = (float*)d_out;

    dim3 grid(kB);
    dim3 block(64);
    adf_kernel<<<grid, block, 0, stream>>>(u_r, u_i, x_r, x_i,
                                           w0_r, w0_i, f0_r, f0_i, out);
}

// Round 6
// 1188.108 us; speedup vs baseline: 1.2323x; 1.2323x over previous
//
#include <hip/hip_runtime.h>

namespace {

constexpr int kB = 64;
constexpr int kL = 4096;
constexpr float kLrW = 1.0f / 64.0f;
constexpr float kLrF = 1.0f / 128.0f;
constexpr float kGradMax = 30.0f;
constexpr float kEps = 1e-9f;
constexpr int kPF = 8;
constexpr int kNC = kL / kPF;

#define DPP_ADD_F32(v, ctrl)                                                   \
    v += __int_as_float(__builtin_amdgcn_update_dpp(                           \
        0, __float_as_int(v), (ctrl), 0xF, 0xF, true))

__device__ __forceinline__ float rl(float v, int l) {
    return __int_as_float(__builtin_amdgcn_readlane(__float_as_int(v), l));
}
__device__ __forceinline__ float frcp(float x) { return __builtin_amdgcn_rcpf(x); }
__device__ __forceinline__ float frsq(float x) { return __builtin_amdgcn_rsqf(x); }

__global__ __launch_bounds__(64, 1) void adf_kernel(
    const float* __restrict__ u_r, const float* __restrict__ u_i,
    const float* __restrict__ x_r, const float* __restrict__ x_i,
    const float* __restrict__ w0r_g, const float* __restrict__ w0i_g,
    const float* __restrict__ f0r_g, const float* __restrict__ f0i_g,
    float* __restrict__ out)
{
    const int b = blockIdx.x;
    const int lane = threadIdx.x;
    const int half = lane >> 5;
    const int tap  = lane & 31;
    const bool lo  = (half == 0);
    const int bIdx = (lane & 32) + 31;     // own-half top lane (31 or 63)

    const int wbase = b * 128 + half * 64 + tap;
    float wAr = w0r_g[wbase],      wAi = w0i_g[wbase];
    float wBr = w0r_g[wbase + 32], wBi = w0i_g[wbase + 32];

    float fr = f0r_g[b * 2 + half];
    float fi = f0i_g[b * 2 + half];

    const float2* __restrict__ ur2 = (const float2*)u_r + (size_t)b * kL * 32;
    const float2* __restrict__ ui2 = (const float2*)u_i + (size_t)b * kL * 32;
    const float2* __restrict__ xr2 = (const float2*)x_r + (size_t)b * kL;
    const float2* __restrict__ xi2 = (const float2*)x_i + (size_t)b * kL;
    float2* __restrict__ ob2 = (float2*)out + (size_t)b * kL * 2;

    float2 AuR[kPF], AuI[kPF], AxR[kPF], AxI[kPF];
    float2 BuR[kPF], BuI[kPF], BxR[kPF], BxI[kPF];
    float Adr[kPF], Adi[kPF], Bdr[kPF], Bdi[kPF];
    float suA[kPF], suB[kPF];
    float kOutR[kPF], kOutI[kPF];

    auto loadChunk = [&](float2 (&uR)[kPF], float2 (&uI)[kPF],
                         float2 (&xR)[kPF], float2 (&xI)[kPF], int chunk) {
#pragma unroll
        for (int s = 0; s < kPF; ++s) {
            int t = chunk * kPF + s;
            t = t < kL ? t : kL - 1;
            uR[s] = ur2[(size_t)t * 32 + tap];
            uI[s] = ui2[(size_t)t * 32 + tap];
            xR[s] = xr2[t];
            xI[s] = xi2[t];
        }
    };

    // Per-chunk: d select + su (8 independent chains, level-major interleave).
    auto calcPre = [&](float2 (&uR)[kPF], float2 (&uI)[kPF],
                       float2 (&xR)[kPF], float2 (&xI)[kPF],
                       float (&dr)[kPF], float (&di)[kPF], float (&su)[kPF]) {
        float e[kPF];
#pragma unroll
        for (int s = 0; s < kPF; ++s) {
            float t0 = uR[s].x * uR[s].x;
            t0 = fmaf(uR[s].y, uR[s].y, t0);
            t0 = fmaf(uI[s].x, uI[s].x, t0);
            t0 = fmaf(uI[s].y, uI[s].y, t0);
            e[s] = t0;
        }
#pragma unroll
        for (int s = 0; s < kPF; ++s) { DPP_ADD_F32(e[s], 0x111); }
#pragma unroll
        for (int s = 0; s < kPF; ++s) { DPP_ADD_F32(e[s], 0x112); }
#pragma unroll
        for (int s = 0; s < kPF; ++s) { DPP_ADD_F32(e[s], 0x114); }
#pragma unroll
        for (int s = 0; s < kPF; ++s) { DPP_ADD_F32(e[s], 0x118); }
#pragma unroll
        for (int s = 0; s < kPF; ++s) { DPP_ADD_F32(e[s], 0x142); }
#pragma unroll
        for (int s = 0; s < kPF; ++s) su[s] = kLrW * frcp(rl(e[s], 31) + kEps);
#pragma unroll
        for (int s = 0; s < kPF; ++s) {
            dr[s] = lo ? xR[s].x : xR[s].y;
            di[s] = lo ? xI[s].x : xI[s].y;
        }
    };

    loadChunk(AuR, AuI, AxR, AxI, 0);
    loadChunk(BuR, BuI, BxR, BxI, 1);

    // ---- pipeline state: prC/piC = reduced partial chains for current t;
    //      psr/psm = psi(t); dpr/dpi = d(t)*psi(t)
    float prC, piC, psr, psm, dpr, dpi;
    {
        const float invf0 = frsq(fmaf(fr, fr, fi * fi));
        psr = fr * invf0;
        psm = -fi * invf0;
        const float d0r = lo ? AxR[0].x : AxR[0].y;
        const float d0i = lo ? AxI[0].x : AxI[0].y;
        dpr = fmaf(d0r, psr, -d0i * psm);
        dpi = fmaf(d0r, psm,  d0i * psr);
        const float2 u0 = AuR[0], q0 = AuI[0];
        float pr = wAr * u0.x;
        pr = fmaf(-wAi, q0.x, pr); pr = fmaf(wBr, u0.y, pr); pr = fmaf(-wBi, q0.y, pr);
        float pi = wAr * q0.x;
        pi = fmaf(wAi, u0.x, pi); pi = fmaf(wBr, q0.y, pi); pi = fmaf(wBi, u0.y, pi);
        DPP_ADD_F32(pr, 0x111); DPP_ADD_F32(pi, 0x111);
        DPP_ADD_F32(pr, 0x112); DPP_ADD_F32(pi, 0x112);
        DPP_ADD_F32(pr, 0x114); DPP_ADD_F32(pi, 0x114);
        DPP_ADD_F32(pr, 0x118); DPP_ADD_F32(pi, 0x118);
        DPP_ADD_F32(pr, 0x142); DPP_ADD_F32(pi, 0x142);
        prC = pr; piC = pi;
    }

    // One pipelined step: consumes prC/piC (v(t)), dpr/dpi, su_s, f, psi;
    // produces reduced chains for t+1 and next-step dpsi.
    auto body = [&](const float2 ucR, const float2 ucI,
                    const float2 unR, const float2 unI,
                    const float dr, const float di,
                    const float dnr, const float dni,
                    const float su_s, float& koR, float& koI) {
        // v(t): broadcast own-half sum (1 ds_bpermute each)
        const float vr = __shfl(prC, bIdx, 64);
        const float vi = __shfl(piC, bIdx, 64);

        // critical chain: ew -> tau -> w -> partials -> red5
        const float ewr = dpr - vr, ewi = dpi - vi;
        const float tr = su_s * ewr, ti = su_s * ewi;

        wAr = fmaf(tr, ucR.x, fmaf(ti, ucI.x, wAr));
        wAi = fmaf(ti, ucR.x, fmaf(-tr, ucI.x, wAi));
        wBr = fmaf(tr, ucR.y, fmaf(ti, ucI.y, wBr));
        wBi = fmaf(ti, ucR.y, fmaf(-tr, ucI.y, wBi));

        float pr = wAr * unR.x;
        pr = fmaf(-wAi, unI.x, pr); pr = fmaf(wBr, unR.y, pr); pr = fmaf(-wBi, unI.y, pr);
        float pi = wAr * unI.x;
        pi = fmaf(wAi, unR.x, pi); pi = fmaf(wBr, unI.y, pi); pi = fmaf(wBi, unR.y, pi);

        // red5 hand-woven with step-t scalar tail
        DPP_ADD_F32(pr, 0x111); DPP_ADD_F32(pi, 0x111);
        const float kr = fmaf(vr, fr, -vi * fi);
        const float ki = fmaf(vr, fi,  vi * fr);
        DPP_ADD_F32(pr, 0x112); DPP_ADD_F32(pi, 0x112);
        koR = kr; koI = ki;
        const float efr = dr - kr, efi = di - ki;
        DPP_ADD_F32(pr, 0x114); DPP_ADD_F32(pi, 0x114);
        float mv2 = vr * vr;
        mv2 = fmaf(vi, vi, mv2);
        DPP_ADD_F32(pr, 0x118); DPP_ADD_F32(pi, 0x118);
        const float ov2 = __shfl_xor(mv2, 32, 64);
        DPP_ADD_F32(pr, 0x142); DPP_ADD_F32(pi, 0x142);
        prC = pr; piC = pi;

        // tail: fills the next body's bpermute/readback shadow
        const float nv = frcp(mv2 + ov2 + kEps);
        float gx = efr * vr; gx = fmaf(efi, vi, gx);
        float gy = efi * vr; gy = fmaf(-efr, vi, gy);
        float gfr = -nv * gx, gfi = -nv * gy;
        float mg = gfr * gfr;
        mg = fmaf(gfi, gfi, mg);
        const float sc = fminf(1.0f, kGradMax * frsq(mg));
        gfr *= sc; gfi *= sc;
        fr = fmaf(-kLrF, gfr, fr);
        fi = fmaf(-kLrF, gfi, fi);
        const float invf = frsq(fmaf(fr, fr, fi * fi));
        psr = fr * invf;
        psm = -fi * invf;
        dpr = fmaf(dnr, psr, -dni * psm);
        dpi = fmaf(dnr, psm,  dni * psr);
    };

    auto processChunk = [&](int tbase,
                            float2 (&uR)[kPF], float2 (&uI)[kPF],
                            float (&dr)[kPF], float (&di)[kPF], float (&su)[kPF],
                            const float2 nR0, const float2 nI0,
                            const float2 nxR0, const float2 nxI0) {
#pragma unroll
        for (int s = 0; s < kPF - 1; ++s)
            body(uR[s], uI[s], uR[s + 1], uI[s + 1], dr[s], di[s],
                 dr[s + 1], di[s + 1], su[s], kOutR[s], kOutI[s]);
        const float dnr = lo ? nxR0.x : nxR0.y;
        const float dni = lo ? nxI0.x : nxI0.y;
        body(uR[kPF - 1], uI[kPF - 1], nR0, nI0, dr[kPF - 1], di[kPF - 1],
             dnr, dni, su[kPF - 1], kOutR[kPF - 1], kOutI[kPF - 1]);
        if (tap == 0) {
#pragma unroll
            for (int s = 0; s < kPF; ++s)
                ob2[(size_t)(tbase + s) * 2 + half] = make_float2(kOutR[s], kOutI[s]);
        }
    };

    for (int c = 0; c < kNC; c += 2) {
        calcPre(AuR, AuI, AxR, AxI, Adr, Adi, suA);
        processChunk(c * kPF, AuR, AuI, Adr, Adi, suA,
                     BuR[0], BuI[0], BxR[0], BxI[0]);
        loadChunk(AuR, AuI, AxR, AxI, (c + 2 < kNC) ? c + 2 : kNC - 1);

        calcPre(BuR, BuI, BxR, BxI, Bdr, Bdi, suB);
        processChunk((c + 1) * kPF, BuR, BuI, Bdr, Bdi, suB,
                     AuR[0], AuI[0], AxR[0], AxI[0]);
        loadChunk(BuR, BuI, BxR, BxI, (c + 3 < kNC) ? c + 3 : kNC - 1);
    }
}

} // namespace

extern "C" void kernel_launch(void* const* d_in, const int* in_sizes, int n_in,
                              void* d_out, int out_size, void* d_ws, size_t ws_size,
                              hipStream_t stream) {
    const float* u_r  = (const float*)d_in[0];
    const float* u_i  = (const float*)d_in[1];
    const float* x_r  = (const float*)d_in[2];
    const float* x_i  = (const float*)d_in[3];
    const float* w0_r = (const float*)d_in[4];
    const float* w0_i = (const float*)d_in[5];
    const float* f0_r = (const float*)d_in[6];
    const float* f0_i = (const float*)d_in[7];
    float* out = (float*)d_out;

    dim3 grid(kB);
    dim3 block(64);
    adf_kernel<<<grid, block, 0, stream>>>(u_r, u_i, x_r, x_i,
                                           w0_r, w0_i, f0_r, f0_i, out);
}

// Round 7
// 838.017 us; speedup vs baseline: 1.7471x; 1.4178x over previous
//
#include <hip/hip_runtime.h>

namespace {

constexpr int kB = 64;
constexpr int kL = 4096;
constexpr float kLrW = 1.0f / 64.0f;
constexpr float kLrF = 1.0f / 128.0f;
constexpr float kGradMax = 30.0f;
constexpr float kEps = 1e-9f;
constexpr int kPF = 8;
constexpr int kNC = kL / kPF;

#define DPP_ADD_F32(v, ctrl)                                                   \
    v += __int_as_float(__builtin_amdgcn_update_dpp(                           \
        0, __float_as_int(v), (ctrl), 0xF, 0xF, true))

__device__ __forceinline__ float rl(float v, int l) {
    return __int_as_float(__builtin_amdgcn_readlane(__float_as_int(v), l));
}
__device__ __forceinline__ float frcp(float x) { return __builtin_amdgcn_rcpf(x); }
__device__ __forceinline__ float frsq(float x) { return __builtin_amdgcn_rsqf(x); }

__global__ __launch_bounds__(64, 1) void adf_kernel(
    const float* __restrict__ u_r, const float* __restrict__ u_i,
    const float* __restrict__ x_r, const float* __restrict__ x_i,
    const float* __restrict__ w0r_g, const float* __restrict__ w0i_g,
    const float* __restrict__ f0r_g, const float* __restrict__ f0i_g,
    float* __restrict__ out)
{
    const int b = blockIdx.x;
    const int lane = threadIdx.x;
    const int half = lane >> 5;       // output mode this lane owns
    const int tap  = lane & 31;
    const bool lo  = (half == 0);

    // w flat: b*128 + i*64 + j*32 + tap ; lane owns w[half][0][tap], w[half][1][tap]
    const int wbase = b * 128 + half * 64 + tap;
    float wAr = w0r_g[wbase],      wAi = w0i_g[wbase];
    float wBr = w0r_g[wbase + 32], wBi = w0i_g[wbase + 32];

    float fr = f0r_g[b * 2 + half];
    float fi = f0i_g[b * 2 + half];
    const float invf0 = frsq(fmaf(fr, fr, fi * fi));
    float psr = fr * invf0, psm = -fi * invf0;   // psi = conj(f)/|f|

    const float2* __restrict__ ur2 = (const float2*)u_r + (size_t)b * kL * 32;
    const float2* __restrict__ ui2 = (const float2*)u_i + (size_t)b * kL * 32;
    const float2* __restrict__ xr2 = (const float2*)x_r + (size_t)b * kL;
    const float2* __restrict__ xi2 = (const float2*)x_i + (size_t)b * kL;
    float2* __restrict__ ob2 = (float2*)out + (size_t)b * kL * 2;

    float2 Au[kPF], Aq[kPF], AxR[kPF], AxI[kPF];
    float2 Bu[kPF], Bq[kPF], BxR[kPF], BxI[kPF];
    float suA[kPF], suB[kPF];
    float kR[kPF], kI[kPF];
    float sdpr = 0.0f, sdpi = 0.0f;   // rolling state: su(t) * d(t) * psi(t)

    auto loadChunk = [&](float2 (&u)[kPF], float2 (&q)[kPF],
                         float2 (&xR)[kPF], float2 (&xI)[kPF], int chunk) {
#pragma unroll
        for (int s = 0; s < kPF; ++s) {
            int t = chunk * kPF + s;
            t = t < kL ? t : kL - 1;
            u[s]  = ur2[(size_t)t * 32 + tap];
            q[s]  = ui2[(size_t)t * 32 + tap];
            xR[s] = xr2[t];
            xI[s] = xi2[t];
        }
        // Pin: the machine scheduler may NOT sink these loads into later
        // compute (that sinking is what destroyed the prefetch in r1-r6:
        // VGPR_Count 48 proved the buffers never materialized).
        __builtin_amdgcn_sched_barrier(0);
    };

    // su = lr_w / (sum|u|^2 + eps); 8 independent chains, level-major.
    auto calcSu = [&](float2 (&u)[kPF], float2 (&q)[kPF], float (&su)[kPF]) {
        float e[kPF];
#pragma unroll
        for (int s = 0; s < kPF; ++s) {
            float t0 = u[s].x * u[s].x;
            t0 = fmaf(u[s].y, u[s].y, t0);
            t0 = fmaf(q[s].x, q[s].x, t0);
            t0 = fmaf(q[s].y, q[s].y, t0);
            e[s] = t0;
        }
#pragma unroll
        for (int s = 0; s < kPF; ++s) { DPP_ADD_F32(e[s], 0x111); }
#pragma unroll
        for (int s = 0; s < kPF; ++s) { DPP_ADD_F32(e[s], 0x112); }
#pragma unroll
        for (int s = 0; s < kPF; ++s) { DPP_ADD_F32(e[s], 0x114); }
#pragma unroll
        for (int s = 0; s < kPF; ++s) { DPP_ADD_F32(e[s], 0x118); }
#pragma unroll
        for (int s = 0; s < kPF; ++s) { DPP_ADD_F32(e[s], 0x142); }
#pragma unroll
        for (int s = 0; s < kPF; ++s) su[s] = kLrW * frcp(rl(e[s], 31) + kEps);
    };

    auto body = [&](int s, float2 (&u)[kPF], float2 (&q)[kPF],
                    float2 (&xR)[kPF], float2 (&xI)[kPF], float (&su)[kPF],
                    bool first) {
        const float2 uc = u[s], qc = q[s];
        if (first) {   // chunk-entry: build sdp from current psi + this chunk's d,su
            const float dr0 = lo ? xR[0].x : xR[0].y;
            const float di0 = lo ? xI[0].x : xI[0].y;
            const float dpr = fmaf(dr0, psr, -di0 * psm);
            const float dpi = fmaf(dr0, psm,  di0 * psr);
            sdpr = su[0] * dpr;
            sdpi = su[0] * dpi;
        }

        // partials for v(t): own-mode dot over (tap, j=0,1)
        float pr = wAr * uc.x;
        pr = fmaf(-wAi, qc.x, pr); pr = fmaf(wBr, uc.y, pr); pr = fmaf(-wBi, qc.y, pr);
        float pi = wAr * qc.x;
        pi = fmaf(wAi, uc.x, pi); pi = fmaf(wBr, qc.y, pi); pi = fmaf(wBi, uc.y, pi);
        DPP_ADD_F32(pr, 0x111); DPP_ADD_F32(pi, 0x111);
        DPP_ADD_F32(pr, 0x112); DPP_ADD_F32(pi, 0x112);
        DPP_ADD_F32(pr, 0x114); DPP_ADD_F32(pi, 0x114);
        DPP_ADD_F32(pr, 0x118); DPP_ADD_F32(pi, 0x118);
        DPP_ADD_F32(pr, 0x142); DPP_ADD_F32(pi, 0x142);
        const float v0r = rl(pr, 31), v1r = rl(pr, 63);
        const float v0i = rl(pi, 31), v1i = rl(pi, 63);
        const float vr = lo ? v0r : v1r;
        const float vi = lo ? v0i : v1i;

        // critical: tau = sdp - su*v, then w update
        const float sun = su[s];
        const float tr = fmaf(-sun, vr, sdpr);
        const float ti = fmaf(-sun, vi, sdpi);
        wAr = fmaf(tr, uc.x, fmaf(ti, qc.x, wAr));
        wAi = fmaf(ti, uc.x, fmaf(-tr, qc.x, wAi));
        wBr = fmaf(tr, uc.y, fmaf(ti, qc.y, wBr));
        wBi = fmaf(ti, uc.y, fmaf(-tr, qc.y, wBi));

        // f-path (has ~1 step of slack before its psi is consumed)
        const float dr = lo ? xR[s].x : xR[s].y;
        const float di = lo ? xI[s].x : xI[s].y;
        const float kr = fmaf(vr, fr, -vi * fi);
        const float ki = fmaf(vr, fi,  vi * fr);
        kR[s] = kr; kI[s] = ki;
        const float efr = dr - kr, efi = di - ki;
        float ven = v0r * v0r;
        ven = fmaf(v0i, v0i, ven);
        ven = fmaf(v1r, v1r, ven);
        ven = fmaf(v1i, v1i, ven);
        const float nv = frcp(ven + kEps);
        float hr = efr * vr; hr = fmaf(efi, vi, hr);     // h = ef*conj(v)/ven = -gf
        float hi = efi * vr; hi = fmaf(-efr, vi, hi);
        hr *= nv; hi *= nv;
        float mg = hr * hr; mg = fmaf(hi, hi, mg);
        const float sc = fminf(1.0f, kGradMax * frsq(mg));  // clip |gf| at 30
        const float scl = kLrF * sc;
        fr = fmaf(scl, hr, fr);                          // f -= lrF*gf
        fi = fmaf(scl, hi, fi);
        const float invf = frsq(fmaf(fr, fr, fi * fi));
        psr = fr * invf; psm = -fi * invf;

        if (s + 1 < kPF) {   // sdp for next step (same chunk)
            const float dnr = lo ? xR[s + 1].x : xR[s + 1].y;
            const float dni = lo ? xI[s + 1].x : xI[s + 1].y;
            const float dpr = fmaf(dnr, psr, -dni * psm);
            const float dpi = fmaf(dnr, psm,  dni * psr);
            sdpr = su[s + 1] * dpr;
            sdpi = su[s + 1] * dpi;
        }
    };

    auto processChunk = [&](int tbase, float2 (&u)[kPF], float2 (&q)[kPF],
                            float2 (&xR)[kPF], float2 (&xI)[kPF], float (&su)[kPF]) {
#pragma unroll
        for (int s = 0; s < kPF; ++s)
            body(s, u, q, xR, xI, su, s == 0);
        if (tap == 0) {
#pragma unroll
            for (int s = 0; s < kPF; ++s)
                ob2[(size_t)(tbase + s) * 2 + half] = make_float2(kR[s], kI[s]);
        }
    };

    loadChunk(Au, Aq, AxR, AxI, 0);
    loadChunk(Bu, Bq, BxR, BxI, 1);
    calcSu(Au, Aq, suA);      // one-time prologue stall, acceptable

    // Rotation per chunk i: process(i) -> load(i+2) -> calcSu(i+1).
    // Every calcSu runs on data loaded >= 1 full chunk earlier; every process
    // on data loaded 2 chunks earlier. No consumer touches a fresh load.
    for (int c = 0; c < kNC; c += 2) {
        processChunk(c * kPF, Au, Aq, AxR, AxI, suA);
        loadChunk(Au, Aq, AxR, AxI, (c + 2 < kNC) ? c + 2 : kNC - 1);
        calcSu(Bu, Bq, suB);
        processChunk((c + 1) * kPF, Bu, Bq, BxR, BxI, suB);
        loadChunk(Bu, Bq, BxR, BxI, (c + 3 < kNC) ? c + 3 : kNC - 1);
        calcSu(Au, Aq, suA);
    }
}

} // namespace

extern "C" void kernel_launch(void* const* d_in, const int* in_sizes, int n_in,
                              void* d_out, int out_size, void* d_ws, size_t ws_size,
                              hipStream_t stream) {
    const float* u_r  = (const float*)d_in[0];
    const float* u_i  = (const float*)d_in[1];
    const float* x_r  = (const float*)d_in[2];
    const float* x_i  = (const float*)d_in[3];
    const float* w0_r = (const float*)d_in[4];
    const float* w0_i = (const float*)d_in[5];
    const float* f0_r = (const float*)d_in[6];
    const float* f0_i = (const float*)d_in[7];
    float* out = (float*)d_out;

    dim3 grid(kB);
    dim3 block(64);
    adf_kernel<<<grid, block, 0, stream>>>(u_r, u_i, x_r, x_i,
                                           w0_r, w0_i, f0_r, f0_i, out);
}